// Round 2
// baseline (370.267 us; speedup 1.0000x reference)
//
#include <hip/hip_runtime.h>

typedef __bf16 bf16_t;
typedef __bf16 bf16x8 __attribute__((ext_vector_type(8)));
typedef __bf16 bf16x4 __attribute__((ext_vector_type(4)));
typedef float  f32x4  __attribute__((ext_vector_type(4)));

#define B_      16
#define L_      2048
#define D_      128
#define QT      16
#define PITCH   2056            // bf16 elems per LDS score row
#define NEGINF  (-1.0e9f)
#define SCALE   0.08838834764831845f   // 1/sqrt(128)

// ---------------------------------------------------------------------------
// Kernel A: pack mask (int32 -> 1 bit) into each block's attn output region;
//           optionally convert K fp32 -> bf16 into workspace.
// One wave per mask row. Packed layout: for block (b,qt), bytes at the start
// of that block's attn region: byte[(row%16)*256 + bc] covers cols bc*8..bc*8+7,
// bit u = col bc*8+u.
// ---------------------------------------------------------------------------
__global__ __launch_bounds__(256) void pack_mask_kernel(
    const int* __restrict__ mask, float* __restrict__ attn,
    const float* __restrict__ k, bf16_t* __restrict__ kb, int has_kb)
{
    const int tid  = threadIdx.x;
    const int l    = tid & 63;
    const int wrow = blockIdx.x * 4 + (tid >> 6);   // 0..32767
    const int b    = wrow >> 11;
    const int r    = wrow & 2047;
    const int qt   = r >> 4;
    const int rr   = r & 15;

    const int* src = mask + ((size_t)b * L_ + r) * (size_t)L_;
    char* region = (char*)(attn + ((size_t)b * L_ + (size_t)qt * QT) * (size_t)L_);

    #pragma unroll 4
    for (int j = 0; j < 32; ++j) {
        int val = src[j * 64 + l];
        unsigned long long bits = __ballot(val != 0);
        if (l == 0) {
            uint2 o; o.x = (unsigned)bits; o.y = (unsigned)(bits >> 32);
            *(uint2*)(region + (size_t)rr * 256 + j * 8) = o;
        }
    }

    if (has_kb) {
        // K: 4M floats -> bf16, f32x4 granularity (1M chunks over 2M threads)
        const int idx = blockIdx.x * 256 + tid;
        const int nchunks = (B_ * L_ * D_) / 4;
        if (idx < nchunks) {
            f32x4 x = *(const f32x4*)(k + (size_t)idx * 4);
            bf16x4 o;
            #pragma unroll
            for (int i = 0; i < 4; ++i) o[i] = (bf16_t)x[i];
            *(bf16x4*)(kb + (size_t)idx * 4) = o;
        }
    }
}

// ---------------------------------------------------------------------------
// Kernel B: V fp32 [B][L][D] -> bf16 VT [B][D][L] (LDS-tiled transpose)
// ---------------------------------------------------------------------------
__global__ __launch_bounds__(256) void vt_kernel(
    const float* __restrict__ v, bf16_t* __restrict__ vt)
{
    __shared__ bf16_t tile[128 * 144];   // [d][l], pitch 144 (288B, 16B-aligned rows)
    const int tid = threadIdx.x;
    const int b   = blockIdx.x >> 4;
    const int l0  = (blockIdx.x & 15) * 128;

    #pragma unroll
    for (int it = 0; it < 16; ++it) {
        int idx = tid + it * 256;        // 4096 f32x4 chunks
        int row = idx >> 5;              // l within tile
        int dc4 = idx & 31;
        f32x4 x = *(const f32x4*)(v + ((size_t)b * L_ + l0 + row) * (size_t)D_ + dc4 * 4);
        #pragma unroll
        for (int i = 0; i < 4; ++i) tile[(dc4 * 4 + i) * 144 + row] = (bf16_t)x[i];
    }
    __syncthreads();
    #pragma unroll
    for (int it = 0; it < 8; ++it) {
        int idx = tid + it * 256;        // 2048 bf16x8 chunks
        int d   = idx >> 4;
        int lc  = idx & 15;
        bf16x8 vec = *(const bf16x8*)&tile[d * 144 + lc * 8];
        *(bf16x8*)(vt + ((size_t)b * D_ + d) * (size_t)L_ + l0 + lc * 8) = vec;
    }
}

// ---------------------------------------------------------------------------
// Main kernel: QT=16 rows per block, 2 blocks/CU, 8 waves.
// ---------------------------------------------------------------------------
__global__ __launch_bounds__(512, 4) void sdpa_kernel(
    const float* __restrict__ q, const float* __restrict__ k,
    const float* __restrict__ v,
    const bf16_t* __restrict__ kb, const bf16_t* __restrict__ vt,
    float* __restrict__ out, float* __restrict__ attn,
    int has_kb, int has_vt)
{
    __shared__ bf16_t sc[QT * PITCH];   // 65,792 B
    __shared__ float  inv_l[QT];

    const int tid = threadIdx.x;
    const int w   = tid >> 6;           // wave 0..7
    const int l   = tid & 63;
    const int li  = l & 15;
    const int lg  = l >> 4;

    // XCD-chunked bijective swizzle (2048 % 8 == 0): each XCD gets 2 batches
    const int bid  = (int)blockIdx.x;
    const int bid2 = (bid & 7) * 256 + (bid >> 3);
    const int b     = bid2 >> 7;        // 128 q-tiles per batch
    const int qtile = bid2 & 127;
    const int qbase = qtile * QT;

    const size_t bq = (size_t)b * L_;
    const float*  qp    = q   + (bq + qbase) * (size_t)D_;
    const float*  kp    = k   + bq * (size_t)D_;
    const float*  vp    = v   + bq * (size_t)D_;
    const bf16_t* kbp   = kb  + bq * (size_t)D_;
    const bf16_t* vtp   = vt  + (size_t)b * D_ * (size_t)L_;
    float*        outp  = out + (bq + qbase) * (size_t)D_;
    float*        attnp = attn + (bq + qbase) * (size_t)L_;

    // ---------------- Phase 0: Q B-fragments (pre-scaled), kept in regs
    bf16x8 aq[4];
    #pragma unroll
    for (int ds = 0; ds < 4; ++ds) {
        const float* p = qp + (size_t)li * D_ + ds * 32 + lg * 8;
        f32x4 x0 = *(const f32x4*)p;
        f32x4 x1 = *(const f32x4*)(p + 4);
        bf16x8 a;
        #pragma unroll
        for (int u = 0; u < 4; ++u) {
            a[u]     = (bf16_t)(x0[u] * SCALE);
            a[4 + u] = (bf16_t)(x1[u] * SCALE);
        }
        aq[ds] = a;
    }

    // ---------------- Phase 1: S^T tiles via mfma(K, Q); store bf16x4 per lane
    // lane li holds S[q=li][kcol = base + lg*4 + r], r=0..3  -> one ds_write_b64
    if (has_kb) {
        bf16x8 KA[4], KB[4];
        auto loadKb = [&](int t, bf16x8* dst) {
            const bf16_t* p = kbp + (size_t)(w * 256 + t * 16 + li) * D_;
            #pragma unroll
            for (int ds = 0; ds < 4; ++ds) dst[ds] = *(const bf16x8*)(p + ds * 32 + lg * 8);
        };
        auto step = [&](int t, bf16x8* kf) {
            f32x4 acc = {0.f, 0.f, 0.f, 0.f};
            #pragma unroll
            for (int ds = 0; ds < 4; ++ds)
                acc = __builtin_amdgcn_mfma_f32_16x16x32_bf16(kf[ds], aq[ds], acc, 0, 0, 0);
            bf16x4 o;
            #pragma unroll
            for (int r = 0; r < 4; ++r) o[r] = (bf16_t)acc[r];
            *(bf16x4*)(sc + (size_t)li * PITCH + w * 256 + t * 16 + lg * 4) = o;
        };
        loadKb(0, KA); loadKb(1, KB);
        #pragma unroll 1
        for (int t = 0; t < 16; t += 2) {
            step(t, KA);
            if (t + 2 < 16) loadKb(t + 2, KA);
            step(t + 1, KB);
            if (t + 3 < 16) loadKb(t + 3, KB);
        }
    } else {
        float kraw[32];
        auto loadKf = [&](int t, float* dst) {
            #pragma unroll
            for (int ds = 0; ds < 4; ++ds) {
                const float* p = kp + (size_t)(w * 256 + t * 16 + li) * D_ + ds * 32 + lg * 8;
                f32x4 x0 = *(const f32x4*)p;
                f32x4 x1 = *(const f32x4*)(p + 4);
                #pragma unroll
                for (int u = 0; u < 4; ++u) { dst[ds*8+u] = x0[u]; dst[ds*8+4+u] = x1[u]; }
            }
        };
        loadKf(0, kraw);
        #pragma unroll 1
        for (int t = 0; t < 16; ++t) {
            bf16x8 kf[4];
            #pragma unroll
            for (int ds = 0; ds < 4; ++ds) {
                bf16x8 a;
                #pragma unroll
                for (int u = 0; u < 8; ++u) a[u] = (bf16_t)kraw[ds*8+u];
                kf[ds] = a;
            }
            if (t + 1 < 16) loadKf(t + 1, kraw);
            f32x4 acc = {0.f, 0.f, 0.f, 0.f};
            #pragma unroll
            for (int ds = 0; ds < 4; ++ds)
                acc = __builtin_amdgcn_mfma_f32_16x16x32_bf16(kf[ds], aq[ds], acc, 0, 0, 0);
            bf16x4 o;
            #pragma unroll
            for (int r = 0; r < 4; ++r) o[r] = (bf16_t)acc[r];
            *(bf16x4*)(sc + (size_t)li * PITCH + w * 256 + t * 16 + lg * 4) = o;
        }
    }
    __syncthreads();

    // ---------------- Phase 2: masked exact softmax (mask from packed bits in attn region)
    {
        const int row = tid >> 5;       // 0..15, 32 threads per row
        const int c   = tid & 31;
        bf16_t* srow = sc + (size_t)row * PITCH;
        const unsigned char* mb = (const unsigned char*)attnp + (size_t)row * 256;

        unsigned int mby[8];
        #pragma unroll
        for (int j = 0; j < 8; ++j) mby[j] = mb[c + j * 32];

        float m = -3.4e38f;
        #pragma unroll
        for (int j = 0; j < 8; ++j) {
            bf16x8 x = *(const bf16x8*)(srow + (c + j * 32) * 8);
            unsigned int bits = mby[j];
            #pragma unroll
            for (int u = 0; u < 8; ++u) {
                float s = (float)x[u] + (((bits >> u) & 1u) ? 0.f : NEGINF);
                m = fmaxf(m, s);
            }
        }
        #pragma unroll
        for (int off = 16; off; off >>= 1) m = fmaxf(m, __shfl_xor(m, off));

        float sum = 0.f;
        #pragma unroll
        for (int j = 0; j < 8; ++j) {
            bf16x8 x = *(bf16x8*)(srow + (c + j * 32) * 8);
            unsigned int bits = mby[j];
            bf16x8 e;
            #pragma unroll
            for (int u = 0; u < 8; ++u) {
                float s  = (float)x[u] + (((bits >> u) & 1u) ? 0.f : NEGINF);
                float ev = __expf(s - m);
                sum += ev;
                e[u] = (bf16_t)ev;
            }
            *(bf16x8*)(srow + (c + j * 32) * 8) = e;
        }
        #pragma unroll
        for (int off = 16; off; off >>= 1) sum += __shfl_xor(sum, off);
        if (c == 0) inv_l[row] = 1.f / sum;
    }
    __syncthreads();

    // ---------------- Phase 3 prologue: issue first V loads before the attn write
    const int d0 = w * 16;
    f32x4 acc3 = {0.f, 0.f, 0.f, 0.f};
    bf16x8 VB0, VB1, VB2, VB3;
    float vr0[8], vr1[8];
    auto loadVT = [&](int ks, bf16x8& dst) {
        dst = *(const bf16x8*)(vtp + (size_t)(d0 + li) * L_ + ks * 32 + lg * 8);
    };
    auto loadVg = [&](int ks, float* dst) {
        const float* p = vp + (size_t)(ks * 32 + lg * 8) * D_ + d0 + li;
        #pragma unroll
        for (int u = 0; u < 8; ++u) dst[u] = p[(size_t)u * D_];
    };
    if (has_vt) { loadVT(0, VB0); loadVT(1, VB1); loadVT(2, VB2); loadVT(3, VB3); }
    else        { loadVg(0, vr0); loadVg(1, vr1); }

    // ---------------- Phase 2b: write normalized attn (fire-and-forget stores)
    {
        #pragma unroll 1
        for (int i = 0; i < 16; ++i) {
            int f  = tid + i * 512;     // float4 index over 16x512
            int rw = f >> 9;
            int c4 = f & 511;
            bf16x4 x = *(const bf16x4*)(sc + (size_t)rw * PITCH + c4 * 4);
            float il = inv_l[rw];
            f32x4 o;
            o[0] = (float)x[0] * il; o[1] = (float)x[1] * il;
            o[2] = (float)x[2] * il; o[3] = (float)x[3] * il;
            *(f32x4*)(attnp + (size_t)rw * L_ + c4 * 4) = o;
        }
    }

    // ---------------- Phase 3: out = (P·V) * inv_l
    if (has_vt) {
        #pragma unroll 1
        for (int ks = 0; ks < 64; ks += 4) {
            bf16x8 a0 = *(const bf16x8*)(sc + (size_t)li * PITCH + ks * 32 + lg * 8);
            acc3 = __builtin_amdgcn_mfma_f32_16x16x32_bf16(a0, VB0, acc3, 0, 0, 0);
            if (ks + 4 < 64) loadVT(ks + 4, VB0);
            bf16x8 a1 = *(const bf16x8*)(sc + (size_t)li * PITCH + (ks + 1) * 32 + lg * 8);
            acc3 = __builtin_amdgcn_mfma_f32_16x16x32_bf16(a1, VB1, acc3, 0, 0, 0);
            if (ks + 5 < 64) loadVT(ks + 5, VB1);
            bf16x8 a2 = *(const bf16x8*)(sc + (size_t)li * PITCH + (ks + 2) * 32 + lg * 8);
            acc3 = __builtin_amdgcn_mfma_f32_16x16x32_bf16(a2, VB2, acc3, 0, 0, 0);
            if (ks + 6 < 64) loadVT(ks + 6, VB2);
            bf16x8 a3 = *(const bf16x8*)(sc + (size_t)li * PITCH + (ks + 3) * 32 + lg * 8);
            acc3 = __builtin_amdgcn_mfma_f32_16x16x32_bf16(a3, VB3, acc3, 0, 0, 0);
            if (ks + 7 < 64) loadVT(ks + 7, VB3);
        }
    } else {
        #pragma unroll 1
        for (int ks = 0; ks < 64; ks += 2) {
            bf16x8 bb;
            #pragma unroll
            for (int u = 0; u < 8; ++u) bb[u] = (bf16_t)vr0[u];
            if (ks + 2 < 64) loadVg(ks + 2, vr0);
            bf16x8 a0 = *(const bf16x8*)(sc + (size_t)li * PITCH + ks * 32 + lg * 8);
            acc3 = __builtin_amdgcn_mfma_f32_16x16x32_bf16(a0, bb, acc3, 0, 0, 0);

            bf16x8 bb1;
            #pragma unroll
            for (int u = 0; u < 8; ++u) bb1[u] = (bf16_t)vr1[u];
            if (ks + 3 < 64) loadVg(ks + 3, vr1);
            bf16x8 a1 = *(const bf16x8*)(sc + (size_t)li * PITCH + (ks + 1) * 32 + lg * 8);
            acc3 = __builtin_amdgcn_mfma_f32_16x16x32_bf16(a1, bb1, acc3, 0, 0, 0);
        }
    }

    {
        const int dcol = d0 + li;
        #pragma unroll
        for (int r = 0; r < 4; ++r) {
            int row = lg * 4 + r;
            outp[(size_t)row * D_ + dcol] = acc3[r] * inv_l[row];
        }
    }
}

extern "C" void kernel_launch(void* const* d_in, const int* in_sizes, int n_in,
                              void* d_out, int out_size, void* d_ws, size_t ws_size,
                              hipStream_t stream) {
    const float* q    = (const float*)d_in[0];
    const float* k    = (const float*)d_in[1];
    const float* v    = (const float*)d_in[2];
    const int*   mask = (const int*)d_in[3];

    float* out  = (float*)d_out;
    float* attn = out + (size_t)B_ * L_ * D_;

    const size_t VT_BYTES = (size_t)B_ * D_ * L_ * 2;   // 8 MB
    const size_t KB_BYTES = (size_t)B_ * L_ * D_ * 2;   // 8 MB
    const int has_vt = ws_size >= VT_BYTES ? 1 : 0;
    const int has_kb = ws_size >= VT_BYTES + KB_BYTES ? 1 : 0;
    bf16_t* vt = (bf16_t*)d_ws;
    bf16_t* kb = (bf16_t*)((char*)d_ws + VT_BYTES);

    // A: pack mask into attn regions (+ K->bf16 if ws allows)
    hipLaunchKernelGGL(pack_mask_kernel, dim3(8192), dim3(256), 0, stream,
                       mask, attn, k, kb, has_kb);
    // B: V -> bf16 transposed [B][D][L]
    if (has_vt)
        hipLaunchKernelGGL(vt_kernel, dim3(256), dim3(256), 0, stream, v, vt);
    // C: main fused attention
    hipLaunchKernelGGL(sdpa_kernel, dim3(2048), dim3(512), 0, stream,
                       q, k, v, kb, vt, out, attn, has_kb, has_vt);
}